// Round 13
// baseline (907.752 us; speedup 1.0000x reference)
//
#include <hip/hip_runtime.h>
#include <hip/hip_bf16.h>

typedef __attribute__((ext_vector_type(4))) float floatx4;
typedef __attribute__((ext_vector_type(8))) __bf16 bf16x8;
typedef unsigned short ushort_t;

#define NENT  700
#define EMB   256
#define KDIM  1024
#define NDIM  512
#define HROWS 720   // 45*16: every row written by hab_kernel; reads stay <= 709
#define NPAIR 340000

// ws byte offsets — total ~7.4 MB
#define WS_HA   0
#define WS_HB   (WS_HA + HROWS*KDIM*2)
#define WS_W2H  (WS_HB + HROWS*KDIM*2)
#define WS_ENT  (WS_W2H + NDIM*KDIM*2)
#define WS_LG   (WS_ENT + NENT*EMB*4)

__device__ __forceinline__ float ldin(const void* p, int i, int isbf) {
    return isbf ? __bfloat162float(((const __hip_bfloat16*)p)[i])
                : ((const float*)p)[i];
}

// per-wave dtype sniff of entity_embedding; deterministic, no cross-kernel dep
__device__ __forceinline__ int detect_bf16(const ushort_t* __restrict__ w) {
    int t = threadIdx.x & 63;
    int e = (w[2*t] >> 7) & 0xFF;
    unsigned long long m = __ballot(e >= 100 && e <= 126);
    return (__popcll(m) >= 48) ? 1 : 0;   // bf16 ~64 hits, f32 ~7
}

// ---------------- stage 1: ent (88 blocks) + W2 repack (256 blocks), one launch ----------------
__global__ void entprep_kernel(const void* __restrict__ E, const void* __restrict__ Went,
                               const void* __restrict__ W2,
                               float* __restrict__ ent, __hip_bfloat16* __restrict__ W2H,
                               void* __restrict__ out) {
    int isbf = detect_bf16((const ushort_t*)E);
    if (blockIdx.x < 88) {
        int ib = blockIdx.x * 8, t = threadIdx.x;
        __shared__ float rows[8][EMB];
#pragma unroll
        for (int r = 0; r < 8; ++r) {
            int i = ib + r;
            rows[r][t] = (i < NENT) ? ldin(E, i*EMB + t, isbf) : 0.f;
        }
        __syncthreads();
        float acc[8] = {0.f,0.f,0.f,0.f,0.f,0.f,0.f,0.f};
        if (isbf) {
            const __hip_bfloat16* W = (const __hip_bfloat16*)Went;
            for (int k = 0; k < EMB; ++k) {
                float w = __bfloat162float(W[k*EMB + t]);
#pragma unroll
                for (int r = 0; r < 8; ++r) acc[r] += rows[r][k] * w;
            }
        } else {
            const float* W = (const float*)Went;
            for (int k = 0; k < EMB; ++k) {
                float w = W[k*EMB + t];
#pragma unroll
                for (int r = 0; r < 8; ++r) acc[r] += rows[r][k] * w;
            }
        }
#pragma unroll
        for (int r = 0; r < 8; ++r) {
            int i = ib + r;
            if (i < NENT) {
                ent[i*EMB + t] = acc[r];
                if (i < 200) {
                    if (isbf) ((__hip_bfloat16*)out)[680000 + i*EMB + t] = __float2bfloat16(acc[r]);
                    else      ((float*)out)[680000 + i*EMB + t] = acc[r];
                }
            }
        }
    } else {
        // W2H: elem ((half*32+kc)*16 + f)*512 + lane*8 + j
        //   = bf16(W2[(kc*32 + (lane>>4)*8 + j)*512 + half*256 + f*16 + (lane&15)])
        int g = (blockIdx.x - 88)*256 + threadIdx.x;     // 65536
        int lane = g & 63, f = (g >> 6) & 15, kc = (g >> 10) & 31, half = g >> 15;
        int l15 = lane & 15, quad = lane >> 4;
        int n = half*256 + f*16 + l15;
        bf16x8 v;
#pragma unroll
        for (int j = 0; j < 8; ++j) {
            int k = kc*32 + quad*8 + j;
            v[j] = (__bf16)ldin(W2, k*NDIM + n, isbf);
        }
        *(bf16x8*)(W2H + (size_t)g*8) = v;
    }
}

// ---------------- stage 2: HA/HB, 16 rows/block ----------------
__global__ void hab_kernel(const float* __restrict__ ent, const void* __restrict__ E,
                           const void* __restrict__ W1, const void* __restrict__ b1,
                           __hip_bfloat16* __restrict__ HA, __hip_bfloat16* __restrict__ HB) {
    int isbf = detect_bf16((const ushort_t*)E);
    int part = blockIdx.y;
    int ib = blockIdx.x * 16;
    int t = threadIdx.x;
    __shared__ float rows[16][EMB];
#pragma unroll
    for (int r = 0; r < 16; ++r) {
        int i = ib + r;
        rows[r][t] = (i < NENT) ? ent[i*EMB + t] : 0.f;
    }
    __syncthreads();
    float acc[16][4];
#pragma unroll
    for (int r = 0; r < 16; ++r)
#pragma unroll
        for (int p = 0; p < 4; ++p) acc[r][p] = 0.f;

    int wbase = part*EMB*KDIM;
    if (isbf) {
        const __hip_bfloat16* W = (const __hip_bfloat16*)W1;
        for (int k = 0; k < EMB; ++k) {
            float w[4];
#pragma unroll
            for (int p = 0; p < 4; ++p) w[p] = __bfloat162float(W[wbase + k*KDIM + t + p*256]);
#pragma unroll
            for (int r = 0; r < 16; ++r) {
                float e = rows[r][k];
#pragma unroll
                for (int p = 0; p < 4; ++p) acc[r][p] += e * w[p];
            }
        }
    } else {
        const float* W = (const float*)W1;
        for (int k = 0; k < EMB; ++k) {
            float w[4];
#pragma unroll
            for (int p = 0; p < 4; ++p) w[p] = W[wbase + k*KDIM + t + p*256];
#pragma unroll
            for (int r = 0; r < 16; ++r) {
                float e = rows[r][k];
#pragma unroll
                for (int p = 0; p < 4; ++p) acc[r][p] += e * w[p];
            }
        }
    }
    __hip_bfloat16* HX = part ? HB : HA;
#pragma unroll
    for (int r = 0; r < 16; ++r) {
#pragma unroll
        for (int p = 0; p < 4; ++p) {
            int n = t + p*256;
            float v = acc[r][p];
            if (!part) v += ldin(b1, n, isbf);
            HX[(ib + r)*KDIM + n] = __float2bfloat16(v);
        }
    }
}

union U8 { bf16x8 v; unsigned u[4]; };

// relu(ha + hb) -> bf16 round-half-up, pair-packed via v_perm
__device__ __forceinline__ bf16x8 mk_af3(bf16x8 ha, bf16x8 hb) {
    U8 r;
#pragma unroll
    for (int j = 0; j < 4; ++j) {
        float x0 = fmaxf((float)ha[2*j]   + (float)hb[2*j],   0.f);
        float x1 = fmaxf((float)ha[2*j+1] + (float)hb[2*j+1], 0.f);
        unsigned u0 = __float_as_uint(x0) + 0x8000u;
        unsigned u1 = __float_as_uint(x1) + 0x8000u;
#if defined(__has_builtin) && __has_builtin(__builtin_amdgcn_perm)
        r.u[j] = __builtin_amdgcn_perm(u1, u0, 0x07060302u);  // {u1.hi16, u0.hi16}
#else
        r.u[j] = (u0 >> 16) | (u1 & 0xFFFF0000u);
#endif
    }
    return r.v;
}

#define MFMA(a, b, c) __builtin_amdgcn_mfma_f32_16x16x32_bf16((a), (b), (c), 0, 0, 0)

// ---------------- main: fused pair MLP — wave-independent K-loop ----------------
// 256 thr = 4 waves; block tile m64 (4i x 16j) x n256 (half = blockIdx.y).
// Wave w: generates ALL 4 A-frags itself (no LDS, no barrier) and owns the
// exclusive n64 slice f = w*4..w*4+3. acc = 4x4x4 = 64 AGPR; 3 waves/SIMD.
// Pipes self-balance: per-kc MFMA ~270 cyc vs VALU ~300 cyc per wave, with
// zero inter-wave coupling -> MFMA/VALU co-issue across the 3 resident waves.
__global__ __launch_bounds__(256, 3) void pair_kernel(
        const ushort_t* __restrict__ HA, const ushort_t* __restrict__ HB,
        const ushort_t* __restrict__ W2H, const void* __restrict__ E,
        const void* __restrict__ b2, const void* __restrict__ W3,
        float* __restrict__ Lg, void* __restrict__ out) {

    const int blkEnd[10] = {650,1300,1800,2300,2800,3450,4100,4594,5088,5582};
    const int aB[10]  = {0,0,0,0,200,200,200,550,400,400};
    const int bB[10]  = {200,0,400,550,400,200,0,0,200,0};
    const int NaT[10] = {200,200,200,200,200,200,200,150,150,150};
    const int NbT[10] = {200,200,150,150,150,200,200,200,200,200};
    const int jTl[10] = {13,13,10,10,10,13,13,13,13,13};
    const int oOf[10] = {0,80000,160000,220000,280000,340000,420000,500000,560000,620000};

    __shared__ float lgt[4][64][2];   // epilogue only

    int bid = blockIdx.x;
    int half = blockIdx.y;
    int ty = 0;
    while (bid >= blkEnd[ty]) ty++;
    int lb = bid - (ty ? blkEnd[ty-1] : 0);
    int jT = jTl[ty];
    int it = lb / jT;
    int jt = lb - it*jT;
    int i0 = aB[ty] + it*4;
    int j0 = bB[ty] + jt*16;

    int tid  = threadIdx.x;
    int lane = tid & 63;
    int w    = tid >> 6;       // 0..3: n64-slice owner
    int l15  = lane & 15;
    int quad = lane >> 4;
    int kb   = (bid*7 + half*3) & 31;   // per-block k stagger (free, keeps L2 decorrelated)

    const char* WB = (const char*)W2H + ((size_t)((half*32)*16 + w*4))*1024 + lane*16;
    const ushort_t* HBp = HB + (j0 + l15)*KDIM + quad*8;   // per-lane hb row
    const ushort_t* HAp = HA + i0*KDIM + quad*8;           // 4 consecutive i rows

    floatx4 acc[4][4];   // [m-frag = i-row][nf]
#pragma unroll
    for (int mf = 0; mf < 4; ++mf)
#pragma unroll
        for (int nf = 0; nf < 4; ++nf) acc[mf][nf] = (floatx4){0.f,0.f,0.f,0.f};

    // prime kc = kb
    bf16x8 Bc0 = *(const bf16x8*)(WB + (size_t)kb*16384);
    bf16x8 Bc1 = *(const bf16x8*)(WB + (size_t)kb*16384 + 1024);
    bf16x8 Bc2 = *(const bf16x8*)(WB + (size_t)kb*16384 + 2048);
    bf16x8 Bc3 = *(const bf16x8*)(WB + (size_t)kb*16384 + 3072);
    bf16x8 af0, af1, af2, af3;
    {
        bf16x8 hb0 = *(const bf16x8*)(HBp + kb*32);
        bf16x8 h0 = *(const bf16x8*)(HAp + kb*32);
        bf16x8 h1 = *(const bf16x8*)(HAp + KDIM + kb*32);
        bf16x8 h2 = *(const bf16x8*)(HAp + 2*KDIM + kb*32);
        bf16x8 h3 = *(const bf16x8*)(HAp + 3*KDIM + kb*32);
        af0 = mk_af3(h0, hb0); af1 = mk_af3(h1, hb0);
        af2 = mk_af3(h2, hb0); af3 = mk_af3(h3, hb0);
    }

#pragma unroll 2
    for (int kc = 0; kc < 32; ++kc) {
        int kn = (kc + 1 + kb) & 31;   // wraps on last iter (harmless re-read)
        // prefetch next kc's operands
        bf16x8 Bn0 = *(const bf16x8*)(WB + (size_t)kn*16384);
        bf16x8 Bn1 = *(const bf16x8*)(WB + (size_t)kn*16384 + 1024);
        bf16x8 Bn2 = *(const bf16x8*)(WB + (size_t)kn*16384 + 2048);
        bf16x8 Bn3 = *(const bf16x8*)(WB + (size_t)kn*16384 + 3072);
        bf16x8 hbn = *(const bf16x8*)(HBp + kn*32);
        bf16x8 hn0 = *(const bf16x8*)(HAp + kn*32);
        bf16x8 hn1 = *(const bf16x8*)(HAp + KDIM + kn*32);
        bf16x8 hn2 = *(const bf16x8*)(HAp + 2*KDIM + kn*32);
        bf16x8 hn3 = *(const bf16x8*)(HAp + 3*KDIM + kn*32);

        // 16 MFMAs on current operands (all independent accumulators)
        acc[0][0] = MFMA(af0, Bc0, acc[0][0]); acc[1][0] = MFMA(af1, Bc0, acc[1][0]);
        acc[2][0] = MFMA(af2, Bc0, acc[2][0]); acc[3][0] = MFMA(af3, Bc0, acc[3][0]);
        acc[0][1] = MFMA(af0, Bc1, acc[0][1]); acc[1][1] = MFMA(af1, Bc1, acc[1][1]);
        acc[2][1] = MFMA(af2, Bc1, acc[2][1]); acc[3][1] = MFMA(af3, Bc1, acc[3][1]);
        acc[0][2] = MFMA(af0, Bc2, acc[0][2]); acc[1][2] = MFMA(af1, Bc2, acc[1][2]);
        acc[2][2] = MFMA(af2, Bc2, acc[2][2]); acc[3][2] = MFMA(af3, Bc2, acc[3][2]);
        acc[0][3] = MFMA(af0, Bc3, acc[0][3]); acc[1][3] = MFMA(af1, Bc3, acc[1][3]);
        acc[2][3] = MFMA(af2, Bc3, acc[2][3]); acc[3][3] = MFMA(af3, Bc3, acc[3][3]);

        // generate next A-frags (VALU; overlaps MFMA pipe drain of other waves)
        af0 = mk_af3(hn0, hbn); af1 = mk_af3(hn1, hbn);
        af2 = mk_af3(hn2, hbn); af3 = mk_af3(hn3, hbn);
        Bc0 = Bn0; Bc1 = Bn1; Bc2 = Bn2; Bc3 = Bn3;
    }

    // epilogue: h2 = relu(acc + b2); partial logits over this wave's n64; LDS reduce
    int isbf = detect_bf16((const ushort_t*)E);
    int nb = half*256 + w*64;
    float b2v[4], wa[4], wb[4];
#pragma unroll
    for (int nf = 0; nf < 4; ++nf) {
        int n = nb + nf*16 + l15;
        b2v[nf] = ldin(b2, n, isbf);
        wa[nf]  = ldin(W3, 2*n, isbf);
        wb[nf]  = ldin(W3, 2*n+1, isbf);
    }
#pragma unroll
    for (int mf = 0; mf < 4; ++mf) {
        float s0[4] = {0.f,0.f,0.f,0.f};
        float s1[4] = {0.f,0.f,0.f,0.f};
#pragma unroll
        for (int nf = 0; nf < 4; ++nf) {
            floatx4 c = acc[mf][nf];
#pragma unroll
            for (int r = 0; r < 4; ++r) {
                float v = fmaxf(c[r] + b2v[nf], 0.f);
                s0[r] += v * wa[nf];
                s1[r] += v * wb[nf];
            }
        }
#pragma unroll
        for (int off = 1; off < 16; off <<= 1) {
#pragma unroll
            for (int r = 0; r < 4; ++r) {
                s0[r] += __shfl_xor(s0[r], off, 64);
                s1[r] += __shfl_xor(s1[r], off, 64);
            }
        }
        if (l15 == 0) {
#pragma unroll
            for (int r = 0; r < 4; ++r) {
                int p = mf*16 + quad*4 + r;   // i_local*16 + j_local
                lgt[w][p][0] = s0[r];
                lgt[w][p][1] = s1[r];
            }
        }
    }
    __syncthreads();

    if (tid < 64) {
        int p = tid;
        float l0 = lgt[0][p][0] + lgt[1][p][0] + lgt[2][p][0] + lgt[3][p][0];
        float l1 = lgt[0][p][1] + lgt[1][p][1] + lgt[2][p][1] + lgt[3][p][1];
        int pi = it*4 + (p >> 4), pj = jt*16 + (p & 15);
        if (pi < NaT[ty] && pj < NbT[ty]) {
            int o = oOf[ty] + (pi*NbT[ty] + pj)*2;
            if (half == 0) {
                if (isbf) {
                    __hip_bfloat16* ob = (__hip_bfloat16*)out;
                    ob[o] = __float2bfloat16(l0); ob[o+1] = __float2bfloat16(l1);
                } else {
                    float* of = (float*)out;
                    of[o] = l0; of[o+1] = l1;
                }
            } else {
                Lg[o] = l0; Lg[o+1] = l1;
            }
        }
    }
}

// ---------------- final: combine halves + b3, softmax, store ----------------
__global__ void final_kernel(const float* __restrict__ Lg, const void* __restrict__ b3,
                             const void* __restrict__ E, void* __restrict__ out) {
    int isbf = detect_bf16((const ushort_t*)E);
    int g = blockIdx.x*512 + threadIdx.x;
    if (g >= NPAIR) return;
    float h0, h1;
    if (isbf) {
        h0 = __bfloat162float(((const __hip_bfloat16*)out)[2*g]);
        h1 = __bfloat162float(((const __hip_bfloat16*)out)[2*g+1]);
    } else {
        h0 = ((const float*)out)[2*g];
        h1 = ((const float*)out)[2*g+1];
    }
    float l0 = h0 + Lg[2*g]   + ldin(b3, 0, isbf);
    float l1 = h1 + Lg[2*g+1] + ldin(b3, 1, isbf);
    float mx = fmaxf(l0, l1);
    float e0 = __expf(l0 - mx), e1 = __expf(l1 - mx);
    float inv = 1.f / (e0 + e1);
    if (isbf) {
        __hip_bfloat16* ob = (__hip_bfloat16*)out;
        ob[2*g]   = __float2bfloat16(e0 * inv);
        ob[2*g+1] = __float2bfloat16(e1 * inv);
    } else {
        float* of = (float*)out;
        of[2*g]   = e0 * inv;
        of[2*g+1] = e1 * inv;
    }
}

extern "C" void kernel_launch(void* const* d_in, const int* in_sizes, int n_in,
                              void* d_out, int out_size, void* d_ws, size_t ws_size,
                              hipStream_t stream) {
    const void* E    = d_in[1];
    const void* Went = d_in[3];
    const void* W1   = d_in[5];
    const void* b1   = d_in[6];
    const void* W2   = d_in[7];
    const void* b2   = d_in[8];
    const void* W3   = d_in[9];
    const void* b3   = d_in[10];

    char* ws = (char*)d_ws;
    __hip_bfloat16* HA   = (__hip_bfloat16*)(ws + WS_HA);
    __hip_bfloat16* HB   = (__hip_bfloat16*)(ws + WS_HB);
    __hip_bfloat16* W2H  = (__hip_bfloat16*)(ws + WS_W2H);
    float*          entf = (float*)(ws + WS_ENT);
    float*          Lg   = (float*)(ws + WS_LG);

    entprep_kernel<<<dim3(344), dim3(256), 0, stream>>>(E, Went, W2, entf, W2H, d_out);
    hab_kernel<<<dim3(45, 2), dim3(256), 0, stream>>>(entf, E, W1, b1, HA, HB);
    pair_kernel<<<dim3(5582, 2), dim3(256), 0, stream>>>((const ushort_t*)HA, (const ushort_t*)HB,
                                                         (const ushort_t*)W2H, E, b2, W3, Lg, d_out);
    final_kernel<<<dim3((NPAIR + 511)/512), dim3(512), 0, stream>>>(Lg, b3, E, d_out);
}

// Round 14
// 561.343 us; speedup vs baseline: 1.6171x; 1.6171x over previous
//
#include <hip/hip_runtime.h>
#include <hip/hip_bf16.h>

typedef __attribute__((ext_vector_type(4))) float floatx4;
typedef __attribute__((ext_vector_type(8))) __bf16 bf16x8;
typedef unsigned short ushort_t;

#define NENT  700
#define EMB   256
#define KDIM  1024
#define NDIM  512
#define HROWS 720   // 45*16: every row written by hab_kernel; reads stay <= 709
#define NPAIR 340000

// ws byte offsets — total ~7.4 MB
#define WS_HA   0
#define WS_HB   (WS_HA + HROWS*KDIM*2)
#define WS_W2H  (WS_HB + HROWS*KDIM*2)
#define WS_ENT  (WS_W2H + NDIM*KDIM*2)
#define WS_LG   (WS_ENT + NENT*EMB*4)

__device__ __forceinline__ float ldin(const void* p, int i, int isbf) {
    return isbf ? __bfloat162float(((const __hip_bfloat16*)p)[i])
                : ((const float*)p)[i];
}

// per-wave dtype sniff of entity_embedding; deterministic, no cross-kernel dep
__device__ __forceinline__ int detect_bf16(const ushort_t* __restrict__ w) {
    int t = threadIdx.x & 63;
    int e = (w[2*t] >> 7) & 0xFF;
    unsigned long long m = __ballot(e >= 100 && e <= 126);
    return (__popcll(m) >= 48) ? 1 : 0;   // bf16 ~64 hits, f32 ~7
}

// lgkmcnt(0) only; vmcnt untouched -> global prefetches survive the barrier
#define LDS_BARRIER() do { __builtin_amdgcn_s_waitcnt(0xC07F); __builtin_amdgcn_s_barrier(); } while (0)

// ---------------- stage 1: ent (88 blocks) + W2 repack (256 blocks), one launch ----------------
__global__ void entprep_kernel(const void* __restrict__ E, const void* __restrict__ Went,
                               const void* __restrict__ W2,
                               float* __restrict__ ent, __hip_bfloat16* __restrict__ W2H,
                               void* __restrict__ out) {
    int isbf = detect_bf16((const ushort_t*)E);
    if (blockIdx.x < 88) {
        int ib = blockIdx.x * 8, t = threadIdx.x;
        __shared__ float rows[8][EMB];
#pragma unroll
        for (int r = 0; r < 8; ++r) {
            int i = ib + r;
            rows[r][t] = (i < NENT) ? ldin(E, i*EMB + t, isbf) : 0.f;
        }
        __syncthreads();
        float acc[8] = {0.f,0.f,0.f,0.f,0.f,0.f,0.f,0.f};
        if (isbf) {
            const __hip_bfloat16* W = (const __hip_bfloat16*)Went;
            for (int k = 0; k < EMB; ++k) {
                float w = __bfloat162float(W[k*EMB + t]);
#pragma unroll
                for (int r = 0; r < 8; ++r) acc[r] += rows[r][k] * w;
            }
        } else {
            const float* W = (const float*)Went;
            for (int k = 0; k < EMB; ++k) {
                float w = W[k*EMB + t];
#pragma unroll
                for (int r = 0; r < 8; ++r) acc[r] += rows[r][k] * w;
            }
        }
#pragma unroll
        for (int r = 0; r < 8; ++r) {
            int i = ib + r;
            if (i < NENT) {
                ent[i*EMB + t] = acc[r];
                if (i < 200) {
                    if (isbf) ((__hip_bfloat16*)out)[680000 + i*EMB + t] = __float2bfloat16(acc[r]);
                    else      ((float*)out)[680000 + i*EMB + t] = acc[r];
                }
            }
        }
    } else {
        // W2H: elem ((half*32+kc)*16 + f)*512 + lane*8 + j
        //   = bf16(W2[(kc*32 + (lane>>4)*8 + j)*512 + half*256 + f*16 + (lane&15)])
        int g = (blockIdx.x - 88)*256 + threadIdx.x;     // 65536
        int lane = g & 63, f = (g >> 6) & 15, kc = (g >> 10) & 31, half = g >> 15;
        int l15 = lane & 15, quad = lane >> 4;
        int n = half*256 + f*16 + l15;
        bf16x8 v;
#pragma unroll
        for (int j = 0; j < 8; ++j) {
            int k = kc*32 + quad*8 + j;
            v[j] = (__bf16)ldin(W2, k*NDIM + n, isbf);
        }
        *(bf16x8*)(W2H + (size_t)g*8) = v;
    }
}

// ---------------- stage 2: HA/HB, 16 rows/block ----------------
__global__ void hab_kernel(const float* __restrict__ ent, const void* __restrict__ E,
                           const void* __restrict__ W1, const void* __restrict__ b1,
                           __hip_bfloat16* __restrict__ HA, __hip_bfloat16* __restrict__ HB) {
    int isbf = detect_bf16((const ushort_t*)E);
    int part = blockIdx.y;
    int ib = blockIdx.x * 16;
    int t = threadIdx.x;
    __shared__ float rows[16][EMB];
#pragma unroll
    for (int r = 0; r < 16; ++r) {
        int i = ib + r;
        rows[r][t] = (i < NENT) ? ent[i*EMB + t] : 0.f;
    }
    __syncthreads();
    float acc[16][4];
#pragma unroll
    for (int r = 0; r < 16; ++r)
#pragma unroll
        for (int p = 0; p < 4; ++p) acc[r][p] = 0.f;

    int wbase = part*EMB*KDIM;
    if (isbf) {
        const __hip_bfloat16* W = (const __hip_bfloat16*)W1;
        for (int k = 0; k < EMB; ++k) {
            float w[4];
#pragma unroll
            for (int p = 0; p < 4; ++p) w[p] = __bfloat162float(W[wbase + k*KDIM + t + p*256]);
#pragma unroll
            for (int r = 0; r < 16; ++r) {
                float e = rows[r][k];
#pragma unroll
                for (int p = 0; p < 4; ++p) acc[r][p] += e * w[p];
            }
        }
    } else {
        const float* W = (const float*)W1;
        for (int k = 0; k < EMB; ++k) {
            float w[4];
#pragma unroll
            for (int p = 0; p < 4; ++p) w[p] = W[wbase + k*KDIM + t + p*256];
#pragma unroll
            for (int r = 0; r < 16; ++r) {
                float e = rows[r][k];
#pragma unroll
                for (int p = 0; p < 4; ++p) acc[r][p] += e * w[p];
            }
        }
    }
    __hip_bfloat16* HX = part ? HB : HA;
#pragma unroll
    for (int r = 0; r < 16; ++r) {
#pragma unroll
        for (int p = 0; p < 4; ++p) {
            int n = t + p*256;
            float v = acc[r][p];
            if (!part) v += ldin(b1, n, isbf);
            HX[(ib + r)*KDIM + n] = __float2bfloat16(v);
        }
    }
}

union U8 { bf16x8 v; unsigned u[4]; };

// relu(ha + hb) -> bf16 round-half-up, pair-packed via v_perm
__device__ __forceinline__ bf16x8 mk_af3(bf16x8 ha, bf16x8 hb) {
    U8 r;
#pragma unroll
    for (int j = 0; j < 4; ++j) {
        float x0 = fmaxf((float)ha[2*j]   + (float)hb[2*j],   0.f);
        float x1 = fmaxf((float)ha[2*j+1] + (float)hb[2*j+1], 0.f);
        unsigned u0 = __float_as_uint(x0) + 0x8000u;
        unsigned u1 = __float_as_uint(x1) + 0x8000u;
#if defined(__has_builtin) && __has_builtin(__builtin_amdgcn_perm)
        r.u[j] = __builtin_amdgcn_perm(u1, u0, 0x07060302u);  // {u1.hi16, u0.hi16}
#else
        r.u[j] = (u0 >> 16) | (u1 & 0xFFFF0000u);
#endif
    }
    return r.v;
}

#define MFMA(a, b, c) __builtin_amdgcn_mfma_f32_16x16x32_bf16((a), (b), (c), 0, 0, 0)

// ---------------- main: fused pair MLP (R12 = best-known: A-shared LDS, 2kc phases, k-stagger) ----------------
__global__ __launch_bounds__(256, 3) void pair_kernel(
        const ushort_t* __restrict__ HA, const ushort_t* __restrict__ HB,
        const ushort_t* __restrict__ W2H, const void* __restrict__ E,
        const void* __restrict__ b2, const void* __restrict__ W3,
        float* __restrict__ Lg, void* __restrict__ out) {

    const int blkEnd[10] = {650,1300,1800,2300,2800,3450,4100,4594,5088,5582};
    const int aB[10]  = {0,0,0,0,200,200,200,550,400,400};
    const int bB[10]  = {200,0,400,550,400,200,0,0,200,0};
    const int NaT[10] = {200,200,200,200,200,200,200,150,150,150};
    const int NbT[10] = {200,200,150,150,150,200,200,200,200,200};
    const int jTl[10] = {13,13,10,10,10,13,13,13,13,13};
    const int oOf[10] = {0,80000,160000,220000,280000,340000,420000,500000,560000,620000};

    __shared__ __align__(16) unsigned char sAF[16384];  // 2 phases x (2 kc x 4 frags x 1 KB)
    __shared__ float lgt[4][64][2];

    int bid = blockIdx.x;
    int half = blockIdx.y;
    int ty = 0;
    while (bid >= blkEnd[ty]) ty++;
    int lb = bid - (ty ? blkEnd[ty-1] : 0);
    int jT = jTl[ty];
    int it = lb / jT;
    int jt = lb - it*jT;
    int i0 = aB[ty] + it*4;
    int j0 = bB[ty] + jt*16;

    int tid  = threadIdx.x;
    int lane = tid & 63;
    int w    = tid >> 6;       // 0..3: A-frag owner AND n64-slice owner
    int l15  = lane & 15;
    int quad = lane >> 4;
    int kb   = (bid*7 + half*3) & 31;   // per-block k-phase stagger

    const char* WB = (const char*)W2H + ((size_t)((half*32)*16 + w*4))*1024 + lane*16;
    const ushort_t* HBp = HB + (j0 + l15)*KDIM + quad*8;
    const ushort_t* HAp = HA + (i0 + w)*KDIM + quad*8;

    floatx4 acc[4][4];
#pragma unroll
    for (int mf = 0; mf < 4; ++mf)
#pragma unroll
        for (int nf = 0; nf < 4; ++nf) acc[mf][nf] = (floatx4){0.f,0.f,0.f,0.f};

    int k0 = kb, k1 = (kb + 1) & 31;
    bf16x8 Bc0 = *(const bf16x8*)(WB + (size_t)k0*16384);
    bf16x8 Bc1 = *(const bf16x8*)(WB + (size_t)k0*16384 + 1024);
    bf16x8 Bc2 = *(const bf16x8*)(WB + (size_t)k0*16384 + 2048);
    bf16x8 Bc3 = *(const bf16x8*)(WB + (size_t)k0*16384 + 3072);
    bf16x8 Bn0 = *(const bf16x8*)(WB + (size_t)k1*16384);
    bf16x8 Bn1 = *(const bf16x8*)(WB + (size_t)k1*16384 + 1024);
    bf16x8 Bn2 = *(const bf16x8*)(WB + (size_t)k1*16384 + 2048);
    bf16x8 Bn3 = *(const bf16x8*)(WB + (size_t)k1*16384 + 3072);
    bf16x8 haA = *(const bf16x8*)(HAp + k0*32);
    bf16x8 haB = *(const bf16x8*)(HAp + k1*32);
    bf16x8 hbA = *(const bf16x8*)(HBp + k0*32);
    bf16x8 hbB = *(const bf16x8*)(HBp + k1*32);

#pragma unroll 2
    for (int ph = 0; ph < 16; ++ph) {
        int kn2 = (2*ph + 2 + kb) & 31;   // wraps (harmless re-read on last phases)
        int kn3 = (2*ph + 3 + kb) & 31;
        // next-phase ha/hb prefetch (full-phase distance)
        bf16x8 nhaA = *(const bf16x8*)(HAp + kn2*32);
        bf16x8 nhaB = *(const bf16x8*)(HAp + kn3*32);
        bf16x8 nhbA = *(const bf16x8*)(HBp + kn2*32);
        bf16x8 nhbB = *(const bf16x8*)(HBp + kn3*32);

        // A-gen: this wave's fragment for both sub-kc -> LDS
        char* sW = (char*)sAF + (ph & 1)*8192 + w*1024 + lane*16;
        *(bf16x8*)(sW)        = mk_af3(haA, hbA);
        *(bf16x8*)(sW + 4096) = mk_af3(haB, hbB);
        LDS_BARRIER();

        const char* sR = (const char*)sAF + (ph & 1)*8192 + lane*16;
        // sub 0
        {
            bf16x8 a0 = *(const bf16x8*)(sR);
            bf16x8 a1 = *(const bf16x8*)(sR + 1024);
            bf16x8 a2 = *(const bf16x8*)(sR + 2048);
            bf16x8 a3 = *(const bf16x8*)(sR + 3072);
            acc[0][0] = MFMA(a0, Bc0, acc[0][0]); acc[1][0] = MFMA(a1, Bc0, acc[1][0]);
            acc[2][0] = MFMA(a2, Bc0, acc[2][0]); acc[3][0] = MFMA(a3, Bc0, acc[3][0]);
            acc[0][1] = MFMA(a0, Bc1, acc[0][1]); acc[1][1] = MFMA(a1, Bc1, acc[1][1]);
            acc[2][1] = MFMA(a2, Bc1, acc[2][1]); acc[3][1] = MFMA(a3, Bc1, acc[3][1]);
            acc[0][2] = MFMA(a0, Bc2, acc[0][2]); acc[1][2] = MFMA(a1, Bc2, acc[1][2]);
            acc[2][2] = MFMA(a2, Bc2, acc[2][2]); acc[3][2] = MFMA(a3, Bc2, acc[3][2]);
            acc[0][3] = MFMA(a0, Bc3, acc[0][3]); acc[1][3] = MFMA(a1, Bc3, acc[1][3]);
            acc[2][3] = MFMA(a2, Bc3, acc[2][3]); acc[3][3] = MFMA(a3, Bc3, acc[3][3]);
        }
        Bc0 = *(const bf16x8*)(WB + (size_t)kn2*16384);
        Bc1 = *(const bf16x8*)(WB + (size_t)kn2*16384 + 1024);
        Bc2 = *(const bf16x8*)(WB + (size_t)kn2*16384 + 2048);
        Bc3 = *(const bf16x8*)(WB + (size_t)kn2*16384 + 3072);
        // sub 1
        {
            bf16x8 a0 = *(const bf16x8*)(sR + 4096);
            bf16x8 a1 = *(const bf16x8*)(sR + 4096 + 1024);
            bf16x8 a2 = *(const bf16x8*)(sR + 4096 + 2048);
            bf16x8 a3 = *(const bf16x8*)(sR + 4096 + 3072);
            acc[0][0] = MFMA(a0, Bn0, acc[0][0]); acc[1][0] = MFMA(a1, Bn0, acc[1][0]);
            acc[2][0] = MFMA(a2, Bn0, acc[2][0]); acc[3][0] = MFMA(a3, Bn0, acc[3][0]);
            acc[0][1] = MFMA(a0, Bn1, acc[0][1]); acc[1][1] = MFMA(a1, Bn1, acc[1][1]);
            acc[2][1] = MFMA(a2, Bn1, acc[2][1]); acc[3][1] = MFMA(a3, Bn1, acc[3][1]);
            acc[0][2] = MFMA(a0, Bn2, acc[0][2]); acc[1][2] = MFMA(a1, Bn2, acc[1][2]);
            acc[2][2] = MFMA(a2, Bn2, acc[2][2]); acc[3][2] = MFMA(a3, Bn2, acc[3][2]);
            acc[0][3] = MFMA(a0, Bn3, acc[0][3]); acc[1][3] = MFMA(a1, Bn3, acc[1][3]);
            acc[2][3] = MFMA(a2, Bn3, acc[2][3]); acc[3][3] = MFMA(a3, Bn3, acc[3][3]);
        }
        Bn0 = *(const bf16x8*)(WB + (size_t)kn3*16384);
        Bn1 = *(const bf16x8*)(WB + (size_t)kn3*16384 + 1024);
        Bn2 = *(const bf16x8*)(WB + (size_t)kn3*16384 + 2048);
        Bn3 = *(const bf16x8*)(WB + (size_t)kn3*16384 + 3072);

        haA = nhaA; haB = nhaB; hbA = nhbA; hbB = nhbB;
    }

    // epilogue: h2 = relu(acc + b2); partial logits over this wave's n64; LDS reduce
    int isbf = detect_bf16((const ushort_t*)E);
    int nb = half*256 + w*64;
    float b2v[4], wa[4], wb[4];
#pragma unroll
    for (int nf = 0; nf < 4; ++nf) {
        int n = nb + nf*16 + l15;
        b2v[nf] = ldin(b2, n, isbf);
        wa[nf]  = ldin(W3, 2*n, isbf);
        wb[nf]  = ldin(W3, 2*n+1, isbf);
    }
#pragma unroll
    for (int mf = 0; mf < 4; ++mf) {
        float s0[4] = {0.f,0.f,0.f,0.f};
        float s1[4] = {0.f,0.f,0.f,0.f};
#pragma unroll
        for (int nf = 0; nf < 4; ++nf) {
            floatx4 c = acc[mf][nf];
#pragma unroll
            for (int r = 0; r < 4; ++r) {
                float v = fmaxf(c[r] + b2v[nf], 0.f);
                s0[r] += v * wa[nf];
                s1[r] += v * wb[nf];
            }
        }
#pragma unroll
        for (int off = 1; off < 16; off <<= 1) {
#pragma unroll
            for (int r = 0; r < 4; ++r) {
                s0[r] += __shfl_xor(s0[r], off, 64);
                s1[r] += __shfl_xor(s1[r], off, 64);
            }
        }
        if (l15 == 0) {
#pragma unroll
            for (int r = 0; r < 4; ++r) {
                int p = mf*16 + quad*4 + r;
                lgt[w][p][0] = s0[r];
                lgt[w][p][1] = s1[r];
            }
        }
    }
    __syncthreads();

    if (tid < 64) {
        int p = tid;
        float l0 = lgt[0][p][0] + lgt[1][p][0] + lgt[2][p][0] + lgt[3][p][0];
        float l1 = lgt[0][p][1] + lgt[1][p][1] + lgt[2][p][1] + lgt[3][p][1];
        int pi = it*4 + (p >> 4), pj = jt*16 + (p & 15);
        if (pi < NaT[ty] && pj < NbT[ty]) {
            int o = oOf[ty] + (pi*NbT[ty] + pj)*2;
            if (half == 0) {
                if (isbf) {
                    __hip_bfloat16* ob = (__hip_bfloat16*)out;
                    ob[o] = __float2bfloat16(l0); ob[o+1] = __float2bfloat16(l1);
                } else {
                    float* of = (float*)out;
                    of[o] = l0; of[o+1] = l1;
                }
            } else {
                Lg[o] = l0; Lg[o+1] = l1;
            }
        }
    }
}

// ---------------- final: combine halves + b3, softmax, store ----------------
__global__ void final_kernel(const float* __restrict__ Lg, const void* __restrict__ b3,
                             const void* __restrict__ E, void* __restrict__ out) {
    int isbf = detect_bf16((const ushort_t*)E);
    int g = blockIdx.x*512 + threadIdx.x;
    if (g >= NPAIR) return;
    float h0, h1;
    if (isbf) {
        h0 = __bfloat162float(((const __hip_bfloat16*)out)[2*g]);
        h1 = __bfloat162float(((const __hip_bfloat16*)out)[2*g+1]);
    } else {
        h0 = ((const float*)out)[2*g];
        h1 = ((const float*)out)[2*g+1];
    }
    float l0 = h0 + Lg[2*g]   + ldin(b3, 0, isbf);
    float l1 = h1 + Lg[2*g+1] + ldin(b3, 1, isbf);
    float mx = fmaxf(l0, l1);
    float e0 = __expf(l0 - mx), e1 = __expf(l1 - mx);
    float inv = 1.f / (e0 + e1);
    if (isbf) {
        __hip_bfloat16* ob = (__hip_bfloat16*)out;
        ob[2*g]   = __float2bfloat16(e0 * inv);
        ob[2*g+1] = __float2bfloat16(e1 * inv);
    } else {
        float* of = (float*)out;
        of[2*g]   = e0 * inv;
        of[2*g+1] = e1 * inv;
    }
}

extern "C" void kernel_launch(void* const* d_in, const int* in_sizes, int n_in,
                              void* d_out, int out_size, void* d_ws, size_t ws_size,
                              hipStream_t stream) {
    const void* E    = d_in[1];
    const void* Went = d_in[3];
    const void* W1   = d_in[5];
    const void* b1   = d_in[6];
    const void* W2   = d_in[7];
    const void* b2   = d_in[8];
    const void* W3   = d_in[9];
    const void* b3   = d_in[10];

    char* ws = (char*)d_ws;
    __hip_bfloat16* HA   = (__hip_bfloat16*)(ws + WS_HA);
    __hip_bfloat16* HB   = (__hip_bfloat16*)(ws + WS_HB);
    __hip_bfloat16* W2H  = (__hip_bfloat16*)(ws + WS_W2H);
    float*          entf = (float*)(ws + WS_ENT);
    float*          Lg   = (float*)(ws + WS_LG);

    entprep_kernel<<<dim3(344), dim3(256), 0, stream>>>(E, Went, W2, entf, W2H, d_out);
    hab_kernel<<<dim3(45, 2), dim3(256), 0, stream>>>(entf, E, W1, b1, HA, HB);
    pair_kernel<<<dim3(5582, 2), dim3(256), 0, stream>>>((const ushort_t*)HA, (const ushort_t*)HB,
                                                         (const ushort_t*)W2H, E, b2, W3, Lg, d_out);
    final_kernel<<<dim3((NPAIR + 511)/512), dim3(512), 0, stream>>>(Lg, b3, E, d_out);
}